// Round 1
// baseline (233.803 us; speedup 1.0000x reference)
//
#include <hip/hip_runtime.h>

typedef __attribute__((ext_vector_type(4))) float f32x4;
typedef __attribute__((ext_vector_type(8))) short short8;

typedef __attribute__((address_space(1))) const void gv_t;
typedef __attribute__((address_space(3))) void lv_t;

__device__ __forceinline__ ushort f2bf(float f) {
  union { float f; unsigned u; } v; v.f = f;
  unsigned r = v.u + 0x7fffu + ((v.u >> 16) & 1u);
  return (ushort)(r >> 16);
}
__device__ __forceinline__ float bf2f(ushort u) {
  union { unsigned u; float f; } v; v.u = ((unsigned)u) << 16;
  return v.f;
}

// ---------------- conversion kernels ----------------
__global__ void k_cvt4(const float* __restrict__ in, ushort* __restrict__ out, int n4) {
  int i = blockIdx.x * blockDim.x + threadIdx.x;
  if (i >= n4) return;
  float4 v = reinterpret_cast<const float4*>(in)[i];
  ushort4 o;
  o.x = f2bf(v.x); o.y = f2bf(v.y); o.z = f2bf(v.z); o.w = f2bf(v.w);
  reinterpret_cast<ushort4*>(out)[i] = o;
}

__global__ void k_bias(const float* __restrict__ bq, const float* __restrict__ bk,
                       const float* __restrict__ bv, float* __restrict__ out) {
  int i = blockIdx.x * blockDim.x + threadIdx.x;
  if (i < 1024) out[i] = bq[i];
  else if (i < 2048) out[i] = bk[i - 1024];
  else if (i < 3072) out[i] = bv[i - 2048];
}

// ---------------- fused QKV projection GEMM ----------------
// C[4096][3072] bf16 = A[4096][1024]bf16 @ W[3072][1024]bf16^T + bias
// m97 structure: 128x128 tile, BK=32, 4 waves (2x2 of 64x64), global_load_lds w=16.
__global__ __launch_bounds__(256) void k_gemm_qkv(
    const ushort* __restrict__ A, const ushort* __restrict__ W,
    const float* __restrict__ bias, ushort* __restrict__ C)
{
  __shared__ __align__(16) ushort As[128 * 32];
  __shared__ __align__(16) ushort Bs[128 * 32];
  const int n0 = blockIdx.x * 128;
  const int m0 = blockIdx.y * 128;
  const int tid = threadIdx.x;
  const int w = tid >> 6, lane = tid & 63;
  const int wr = (w >> 1) * 64, wc = (w & 1) * 64;
  const int lr = lane & 15, lk = (lane >> 4) * 8;

  f32x4 acc[4][4] = {};

  for (int k0 = 0; k0 < 1024; k0 += 32) {
    __syncthreads();
#pragma unroll
    for (int inst = 0; inst < 2; ++inst) {
      int chunk = w * 128 + inst * 64 + lane;
      int row = chunk >> 2, c8 = (chunk & 3) * 8;
      __builtin_amdgcn_global_load_lds(
          (gv_t*)(A + (size_t)(m0 + row) * 1024 + k0 + c8),
          (lv_t*)(As + (size_t)(w * 128 + inst * 64) * 8), 16, 0, 0);
      __builtin_amdgcn_global_load_lds(
          (gv_t*)(W + (size_t)(n0 + row) * 1024 + k0 + c8),
          (lv_t*)(Bs + (size_t)(w * 128 + inst * 64) * 8), 16, 0, 0);
    }
    __syncthreads();
    short8 af[4], bfr[4];
#pragma unroll
    for (int t = 0; t < 4; ++t) {
      af[t]  = *reinterpret_cast<const short8*>(As + (wr + t * 16 + lr) * 32 + lk);
      bfr[t] = *reinterpret_cast<const short8*>(Bs + (wc + t * 16 + lr) * 32 + lk);
    }
#pragma unroll
    for (int mt = 0; mt < 4; ++mt)
#pragma unroll
      for (int nt = 0; nt < 4; ++nt)
        acc[mt][nt] = __builtin_amdgcn_mfma_f32_16x16x32_bf16(af[mt], bfr[nt], acc[mt][nt], 0, 0, 0);
  }

  float bv[4];
#pragma unroll
  for (int nt = 0; nt < 4; ++nt) bv[nt] = bias[n0 + wc + nt * 16 + lr];
#pragma unroll
  for (int mt = 0; mt < 4; ++mt)
#pragma unroll
    for (int nt = 0; nt < 4; ++nt)
#pragma unroll
      for (int j = 0; j < 4; ++j) {
        int row = m0 + wr + mt * 16 + (lane >> 4) * 4 + j;
        int col = n0 + wc + nt * 16 + lr;
        C[(size_t)row * 3072 + col] = f2bf(acc[mt][nt][j] + bv[nt]);
      }
}

// ---------------- fused attention with relative_key_query bias ----------------
// grid (L/64, H, B), 256 threads (4 waves), each wave owns 16 q-rows.
// Per r-tile: S = Q K^T ; T1 = Q Ewin^T ; T2 = K Ewin^T (Ewin = 127 diagonals)
// S += gather(T1,T2); online softmax; O += P V.
__global__ __launch_bounds__(256) void k_attn(
    const ushort* __restrict__ QKV, const ushort* __restrict__ E,
    const float* __restrict__ mask, float* __restrict__ out)
{
  __shared__ __align__(16) ushort Kl[64 * 64];     //  8 KB, swizzled
  __shared__ __align__(16) ushort Vt[64 * 64];     //  8 KB, V^T, swizzled
  __shared__ __align__(16) ushort El[128 * 64];    // 16 KB, E window, swizzled
  __shared__ __align__(16) ushort T1l[64 * 128];   // 16 KB, also holds P (wave-private rows)
  __shared__ __align__(16) ushort T2l[64 * 128];   // 16 KB  -> total 64 KB

  const int lt = blockIdx.x, h = blockIdx.y, b = blockIdx.z;
  const int l0 = lt * 64;
  const int tid = threadIdx.x;
  const int w = tid >> 6, lane = tid & 63;
  const int lr = lane & 15;
  const int lkq = (lane >> 4);      // k-slot quarter index
  const int g4 = (lane >> 4) * 4;   // acc row base

  const ushort* Qg = QKV;
  const ushort* Kg = QKV + 1024;
  const ushort* Vg = QKV + 2048;

  // Q fragments for this wave's 16 rows (reused across all r-tiles)
  short8 qf0, qf1;
  {
    const size_t qoff = (size_t)(b * 1024 + l0 + w * 16 + lr) * 3072 + h * 64;
    qf0 = *reinterpret_cast<const short8*>(Qg + qoff + lkq * 8);
    qf1 = *reinterpret_cast<const short8*>(Qg + qoff + 32 + lkq * 8);
  }

  f32x4 o_[4] = {};
  float m_[4], s_[4];
#pragma unroll
  for (int j = 0; j < 4; ++j) { m_[j] = -1e30f; s_[j] = 0.f; }

  for (int rt = 0; rt < 16; ++rt) {
    const int r0 = rt * 64;
    const int p0 = l0 - r0 + 960;

    // ---- stage K, V^T, E window ----
    {
      int r = tid & 63, c = tid >> 6;  // r: row, c: 16-elem chunk (0..3)
      const ushort* ks = Kg + (size_t)(b * 1024 + r0 + r) * 3072 + h * 64 + c * 16;
      short8 v0 = *reinterpret_cast<const short8*>(ks);
      short8 v1 = *reinterpret_cast<const short8*>(ks + 8);
      *reinterpret_cast<short8*>(Kl + r * 64 + (((c * 2)     ^ (r & 7)) << 3)) = v0;
      *reinterpret_cast<short8*>(Kl + r * 64 + (((c * 2 + 1) ^ (r & 7)) << 3)) = v1;

      const ushort* vs = Vg + (size_t)(b * 1024 + r0 + r) * 3072 + h * 64 + c * 16;
      short8 u0 = *reinterpret_cast<const short8*>(vs);
      short8 u1 = *reinterpret_cast<const short8*>(vs + 8);
#pragma unroll
      for (int i = 0; i < 8; ++i) {
        int n = c * 16 + i;
        Vt[n * 64 + ((((r >> 3) ^ (n & 7)) << 3) | (r & 7))] = (ushort)u0[i];
        n = c * 16 + 8 + i;
        Vt[n * 64 + ((((r >> 3) ^ (n & 7)) << 3) | (r & 7))] = (ushort)u1[i];
      }
#pragma unroll
      for (int half = 0; half < 2; ++half) {
        int dd = (tid >> 2) + half * 64;
        int c2 = tid & 3;
        int p = p0 + dd; p = p > 2046 ? 2046 : p;  // row 127 may clamp; never gathered
        const ushort* es = E + (size_t)p * 64 + c2 * 16;
        short8 e0 = *reinterpret_cast<const short8*>(es);
        short8 e1 = *reinterpret_cast<const short8*>(es + 8);
        *reinterpret_cast<short8*>(El + dd * 64 + (((c2 * 2)     ^ (dd & 7)) << 3)) = e0;
        *reinterpret_cast<short8*>(El + dd * 64 + (((c2 * 2 + 1) ^ (dd & 7)) << 3)) = e1;
      }
    }
    __syncthreads();

    // ---- T1 (own rows: Q·Ewin^T), T2 (rows 16w..: K·Ewin^T) ----
    {
      int krow = w * 16 + lr;
      short8 ka0 = *reinterpret_cast<const short8*>(Kl + krow * 64 + (((lkq)     ^ (krow & 7)) << 3));
      short8 ka1 = *reinterpret_cast<const short8*>(Kl + krow * 64 + (((4 + lkq) ^ (krow & 7)) << 3));
#pragma unroll
      for (int dt = 0; dt < 8; ++dt) {
        int erow = dt * 16 + lr;
        short8 e0 = *reinterpret_cast<const short8*>(El + erow * 64 + (((lkq)     ^ (erow & 7)) << 3));
        short8 e1 = *reinterpret_cast<const short8*>(El + erow * 64 + (((4 + lkq) ^ (erow & 7)) << 3));
        f32x4 z = {0.f, 0.f, 0.f, 0.f};
        f32x4 t1 = __builtin_amdgcn_mfma_f32_16x16x32_bf16(qf0, e0, z, 0, 0, 0);
        t1 = __builtin_amdgcn_mfma_f32_16x16x32_bf16(qf1, e1, t1, 0, 0, 0);
        f32x4 t2 = __builtin_amdgcn_mfma_f32_16x16x32_bf16(ka0, e0, z, 0, 0, 0);
        t2 = __builtin_amdgcn_mfma_f32_16x16x32_bf16(ka1, e1, t2, 0, 0, 0);
#pragma unroll
        for (int j = 0; j < 4; ++j) {
          int er = w * 16 + g4 + j;
          int dc = dt * 16 + lr;
          int swz = ((((dc >> 3) ^ (er & 7)) << 3) | (dc & 7));
          T1l[er * 128 + swz] = f2bf(t1[j]);
          T2l[er * 128 + swz] = f2bf(t2[j]);
        }
      }
    }
    __syncthreads();

    // ---- S assembly: QK^T + gathered bias, scale, mask ----
    float sv[4][4];
#pragma unroll
    for (int ct = 0; ct < 4; ++ct) {
      int krow = ct * 16 + lr;
      short8 kb0 = *reinterpret_cast<const short8*>(Kl + krow * 64 + (((lkq)     ^ (krow & 7)) << 3));
      short8 kb1 = *reinterpret_cast<const short8*>(Kl + krow * 64 + (((4 + lkq) ^ (krow & 7)) << 3));
      f32x4 z = {0.f, 0.f, 0.f, 0.f};
      f32x4 sc = __builtin_amdgcn_mfma_f32_16x16x32_bf16(qf0, kb0, z, 0, 0, 0);
      sc = __builtin_amdgcn_mfma_f32_16x16x32_bf16(qf1, kb1, sc, 0, 0, 0);
      float mk = mask[b * 1024 + r0 + ct * 16 + lr];
#pragma unroll
      for (int j = 0; j < 4; ++j) {
        int e = w * 16 + g4 + j;
        int f = ct * 16 + lr;
        int dd = e - f + 63;  // in [0,126]
        float t1v = bf2f(T1l[e * 128 + ((((dd >> 3) ^ (e & 7)) << 3) | (dd & 7))]);
        float t2v = bf2f(T2l[f * 128 + ((((dd >> 3) ^ (f & 7)) << 3) | (dd & 7))]);
        sv[ct][j] = (sc[j] + t1v + t2v) * 0.125f + mk;
      }
    }

    // ---- online softmax (rows live in 16-lane groups; reduce over lane&15) ----
#pragma unroll
    for (int j = 0; j < 4; ++j) {
      float rm = fmaxf(fmaxf(sv[0][j], sv[1][j]), fmaxf(sv[2][j], sv[3][j]));
      rm = fmaxf(rm, __shfl_xor(rm, 1));
      rm = fmaxf(rm, __shfl_xor(rm, 2));
      rm = fmaxf(rm, __shfl_xor(rm, 4));
      rm = fmaxf(rm, __shfl_xor(rm, 8));
      float mn = fmaxf(m_[j], rm);
      float al = __expf(m_[j] - mn);
      float rs = 0.f;
#pragma unroll
      for (int ct = 0; ct < 4; ++ct) {
        float p = __expf(sv[ct][j] - mn);
        sv[ct][j] = p; rs += p;
      }
      rs += __shfl_xor(rs, 1); rs += __shfl_xor(rs, 2);
      rs += __shfl_xor(rs, 4); rs += __shfl_xor(rs, 8);
      s_[j] = s_[j] * al + rs;
      m_[j] = mn;
#pragma unroll
      for (int vt = 0; vt < 4; ++vt) o_[vt][j] *= al;
    }

    // ---- P -> LDS (alias over this wave's T1 rows; wave-private) ----
#pragma unroll
    for (int ct = 0; ct < 4; ++ct)
#pragma unroll
      for (int j = 0; j < 4; ++j) {
        int er = w * 16 + g4 + j;
        int f = ct * 16 + lr;
        T1l[er * 128 + ((((f >> 3) ^ (er & 7)) << 3) | (f & 7))] = f2bf(sv[ct][j]);
      }

    // ---- PV ----
    {
      int prow = w * 16 + lr;
      short8 pf0 = *reinterpret_cast<const short8*>(T1l + prow * 128 + (((lkq)     ^ (prow & 7)) << 3));
      short8 pf1 = *reinterpret_cast<const short8*>(T1l + prow * 128 + (((4 + lkq) ^ (prow & 7)) << 3));
#pragma unroll
      for (int vt = 0; vt < 4; ++vt) {
        int vrow = vt * 16 + lr;
        short8 vb0 = *reinterpret_cast<const short8*>(Vt + vrow * 64 + (((lkq)     ^ (vrow & 7)) << 3));
        short8 vb1 = *reinterpret_cast<const short8*>(Vt + vrow * 64 + (((4 + lkq) ^ (vrow & 7)) << 3));
        o_[vt] = __builtin_amdgcn_mfma_f32_16x16x32_bf16(pf0, vb0, o_[vt], 0, 0, 0);
        o_[vt] = __builtin_amdgcn_mfma_f32_16x16x32_bf16(pf1, vb1, o_[vt], 0, 0, 0);
      }
    }
    __syncthreads();
  }

  // ---- epilogue: O / s ----
#pragma unroll
  for (int j = 0; j < 4; ++j) {
    float inv = 1.0f / s_[j];
    int row = b * 1024 + l0 + w * 16 + g4 + j;
#pragma unroll
    for (int vt = 0; vt < 4; ++vt) {
      int col = h * 64 + vt * 16 + lr;
      out[(size_t)row * 1024 + col] = o_[vt][j] * inv;
    }
  }
}

// ---------------- host launch ----------------
extern "C" void kernel_launch(void* const* d_in, const int* in_sizes, int n_in,
                              void* d_out, int out_size, void* d_ws, size_t ws_size,
                              hipStream_t stream) {
  const float* hidden = (const float*)d_in[0];
  const float* mask   = (const float*)d_in[1];
  const float* Wq = (const float*)d_in[2];
  const float* bq = (const float*)d_in[3];
  const float* Wk = (const float*)d_in[4];
  const float* bk = (const float*)d_in[5];
  const float* Wv = (const float*)d_in[6];
  const float* bv = (const float*)d_in[7];
  const float* dist = (const float*)d_in[8];
  float* out = (float*)d_out;

  // workspace layout (needs ~40.2 MB)
  char* ws = (char*)d_ws;
  ushort* Hbf  = (ushort*)(ws);                                  //  8,388,608
  ushort* Wqkv = (ushort*)(ws + 8388608);                        //  6,291,456
  float*  Bqkv = (float*) (ws + 8388608 + 6291456);              //     16,384 (12,288 used)
  ushort* Ebf  = (ushort*)(ws + 8388608 + 6291456 + 16384);      //    262,144 (262,016 used)
  ushort* QKV  = (ushort*)(ws + 8388608 + 6291456 + 16384 + 262144); // 25,165,824

  k_cvt4<<<4096, 256, 0, stream>>>(hidden, Hbf, 1048576);
  k_cvt4<<<1024, 256, 0, stream>>>(Wq, Wqkv,           262144);
  k_cvt4<<<1024, 256, 0, stream>>>(Wk, Wqkv + 1048576, 262144);
  k_cvt4<<<1024, 256, 0, stream>>>(Wv, Wqkv + 2097152, 262144);
  k_cvt4<<<128,  256, 0, stream>>>(dist, Ebf, 32752);
  k_bias<<<12,   256, 0, stream>>>(bq, bk, bv, Bqkv);

  k_gemm_qkv<<<dim3(24, 32), 256, 0, stream>>>(Hbf, Wqkv, Bqkv, QKV);
  k_attn<<<dim3(16, 16, 4), 256, 0, stream>>>(QKV, Ebf, mask, out);
}

// Round 3
// 200.848 us; speedup vs baseline: 1.1641x; 1.1641x over previous
//
#include <hip/hip_runtime.h>

typedef __attribute__((ext_vector_type(4))) float f32x4;
typedef __attribute__((ext_vector_type(8))) short short8;
typedef __attribute__((ext_vector_type(2))) unsigned u32x2;

typedef __attribute__((address_space(1))) const void gv_t;
typedef __attribute__((address_space(3))) void lv_t;

__device__ __forceinline__ ushort f2bf(float f) {
  union { float f; unsigned u; } v; v.f = f;
  unsigned r = v.u + 0x7fffu + ((v.u >> 16) & 1u);
  return (ushort)(r >> 16);
}
__device__ __forceinline__ float bf2f(ushort u) {
  union { unsigned u; float f; } v; v.u = ((unsigned)u) << 16;
  return v.f;
}

// ---------------- conversion kernels ----------------
__global__ void k_cvt4(const float* __restrict__ in, ushort* __restrict__ out, int n4) {
  int i = blockIdx.x * blockDim.x + threadIdx.x;
  if (i >= n4) return;
  float4 v = reinterpret_cast<const float4*>(in)[i];
  ushort4 o;
  o.x = f2bf(v.x); o.y = f2bf(v.y); o.z = f2bf(v.z); o.w = f2bf(v.w);
  reinterpret_cast<ushort4*>(out)[i] = o;
}

__global__ void k_bias(const float* __restrict__ bq, const float* __restrict__ bk,
                       const float* __restrict__ bv, float* __restrict__ out) {
  int i = blockIdx.x * blockDim.x + threadIdx.x;
  if (i < 1024) out[i] = bq[i];
  else if (i < 2048) out[i] = bk[i - 1024];
  else if (i < 3072) out[i] = bv[i - 2048];
}

// ---------------- fused QKV projection GEMM (m97 structure, unchanged) ----------------
__global__ __launch_bounds__(256) void k_gemm_qkv(
    const ushort* __restrict__ A, const ushort* __restrict__ W,
    const float* __restrict__ bias, ushort* __restrict__ C)
{
  __shared__ __align__(16) ushort As[128 * 32];
  __shared__ __align__(16) ushort Bs[128 * 32];
  const int n0 = blockIdx.x * 128;
  const int m0 = blockIdx.y * 128;
  const int tid = threadIdx.x;
  const int w = tid >> 6, lane = tid & 63;
  const int wr = (w >> 1) * 64, wc = (w & 1) * 64;
  const int lr = lane & 15, lk = (lane >> 4) * 8;

  f32x4 acc[4][4] = {};

  for (int k0 = 0; k0 < 1024; k0 += 32) {
    __syncthreads();
#pragma unroll
    for (int inst = 0; inst < 2; ++inst) {
      int chunk = w * 128 + inst * 64 + lane;
      int row = chunk >> 2, c8 = (chunk & 3) * 8;
      __builtin_amdgcn_global_load_lds(
          (gv_t*)(A + (size_t)(m0 + row) * 1024 + k0 + c8),
          (lv_t*)(As + (size_t)(w * 128 + inst * 64) * 8), 16, 0, 0);
      __builtin_amdgcn_global_load_lds(
          (gv_t*)(W + (size_t)(n0 + row) * 1024 + k0 + c8),
          (lv_t*)(Bs + (size_t)(w * 128 + inst * 64) * 8), 16, 0, 0);
    }
    __syncthreads();
    short8 af[4], bfr[4];
#pragma unroll
    for (int t = 0; t < 4; ++t) {
      af[t]  = *reinterpret_cast<const short8*>(As + (wr + t * 16 + lr) * 32 + lk);
      bfr[t] = *reinterpret_cast<const short8*>(Bs + (wc + t * 16 + lr) * 32 + lk);
    }
#pragma unroll
    for (int mt = 0; mt < 4; ++mt)
#pragma unroll
      for (int nt = 0; nt < 4; ++nt)
        acc[mt][nt] = __builtin_amdgcn_mfma_f32_16x16x32_bf16(af[mt], bfr[nt], acc[mt][nt], 0, 0, 0);
  }

  float bv[4];
#pragma unroll
  for (int nt = 0; nt < 4; ++nt) bv[nt] = bias[n0 + wc + nt * 16 + lr];
#pragma unroll
  for (int mt = 0; mt < 4; ++mt)
#pragma unroll
    for (int nt = 0; nt < 4; ++nt)
#pragma unroll
      for (int j = 0; j < 4; ++j) {
        int row = m0 + wr + mt * 16 + (lane >> 4) * 4 + j;
        int col = n0 + wc + nt * 16 + lr;
        C[(size_t)row * 3072 + col] = f2bf(acc[mt][nt][j] + bv[nt]);
      }
}

// ---------------- V transpose: QKV V-slice -> VT[(b*16+h)*64 + d][l] ----------------
__global__ __launch_bounds__(256) void k_vt(const ushort* __restrict__ QKV,
                                            ushort* __restrict__ VT) {
  __shared__ ushort t[64][65];
  const int bh = blockIdx.y, b = bh >> 4, h = bh & 15;
  const int l0 = blockIdx.x * 64;
  const int r = threadIdx.x >> 2, c0 = (threadIdx.x & 3) * 16;
  const ushort* src = QKV + (size_t)(b * 1024 + l0 + r) * 3072 + 2048 + h * 64 + c0;
  short8 v0 = *reinterpret_cast<const short8*>(src);
  short8 v1 = *reinterpret_cast<const short8*>(src + 8);
#pragma unroll
  for (int i = 0; i < 8; ++i) {
    t[c0 + i][r] = (ushort)v0[i];
    t[c0 + 8 + i][r] = (ushort)v1[i];
  }
  __syncthreads();
  short8 o0, o1;
#pragma unroll
  for (int i = 0; i < 8; ++i) {
    o0[i] = (short)t[r][c0 + i];
    o1[i] = (short)t[r][c0 + 8 + i];
  }
  ushort* dst = VT + (size_t)(bh * 64 + r) * 1024 + l0 + c0;
  *reinterpret_cast<short8*>(dst) = o0;
  *reinterpret_cast<short8*>(dst + 8) = o1;
}

// ---------------- fused attention with relative_key_query bias ----------------
// grid (L/64, H, B), 256 threads (4 waves), wave w owns q-rows [16w,16w+16).
// S = QK^T; bias1 via in-register T1 (5 local-window frags + shfl gather);
// bias2 via transposed-output T2 -> LDS[f][dd] (vector b64 store, imm-offset scalar read);
// P: row-major swizzled LDS (scalar store, b128 read); V: pre-transposed in global,
// staged via global_load_lds like K, b128 B-fragment reads. No inline asm.
__global__ __launch_bounds__(256) void k_attn(
    const ushort* __restrict__ QKV, const ushort* __restrict__ VTg,
    const ushort* __restrict__ E, const float* __restrict__ mask,
    float* __restrict__ out)
{
  __shared__ __align__(16) ushort Kl[64 * 64];    //  8 KB  row-major, chunk-swizzled
  __shared__ __align__(16) ushort El[128 * 64];   // 16 KB  circular window, chunk-swizzled
  __shared__ __align__(16) ushort Vl[64 * 64];    //  8 KB  V^T rows d x cols f, chunk-swizzled
  __shared__ __align__(16) ushort T2s[64 * 132];  // 16.5KB T2[f][dd] bf16, padded stride
  __shared__ __align__(16) ushort Pp[4 * 1024];   //  8 KB  P row-major swizzled, wave-private

  const int lt = blockIdx.x, h = blockIdx.y, b = blockIdx.z;
  const int bh = b * 16 + h;
  const int l0 = lt * 64;
  const int tid = threadIdx.x;
  const int w = tid >> 6, lane = tid & 63;
  const int g = lane >> 4, m = lane & 15, g4 = g * 4;
  const int rsub = lane >> 3, csub = lane & 7;

  const ushort* Qg = QKV;
  const ushort* Kg = QKV + 1024;
  const float* maskrow = mask + b * 1024;

  // Q fragments (reused all r-tiles)
  short8 qf0, qf1;
  {
    const size_t qoff = (size_t)(b * 1024 + l0 + w * 16 + m) * 3072 + h * 64;
    qf0 = *reinterpret_cast<const short8*>(Qg + qoff + g * 8);
    qf1 = *reinterpret_cast<const short8*>(Qg + qoff + 32 + g * 8);
  }

  // hoisted T1-gather constants (rt/ct-invariant):
  // src lane = (lane&48)|x, x=(g4+j+63-m)&15 ; bsel selects local-window slot
  int srcl[4], bsel[4];
#pragma unroll
  for (int j = 0; j < 4; ++j) {
    int x = (g4 + j + 63 - m) & 15;
    srcl[j] = (lane & 48) | x;
    bsel[j] = (g4 + j) > x;
  }
  // T2 gather: elem addr = A0 + 2096*ct + j  (T2s[f][dd], f=16ct+m, dd=e-f+63)
  const int A0 = 131 * m + g4 + 16 * w + 63;

  // ---- prologue staging: K rows 0..63, E full 128-row window
#pragma unroll
  for (int i = 0; i < 2; ++i) {
    int li = w * 2 + i;
    int kr = li * 8 + rsub;
    __builtin_amdgcn_global_load_lds(
        (gv_t*)(Kg + (size_t)(b * 1024 + kr) * 3072 + h * 64 + ((csub ^ (kr & 7)) << 3)),
        (lv_t*)(Kl + li * 512), 16, 0, 0);
  }
#pragma unroll
  for (int i = 0; i < 4; ++i) {
    int li = w * 4 + i;
    int er = li * 8 + rsub;
    int p = l0 + 960 + er; p = p > 2046 ? 2046 : p;  // clamped row never gathered
    __builtin_amdgcn_global_load_lds(
        (gv_t*)(E + (size_t)p * 64 + ((csub ^ (er & 7)) << 3)),
        (lv_t*)(El + li * 512), 16, 0, 0);
  }

  f32x4 o_[4] = {};
  float m_[4], s_[4];
#pragma unroll
  for (int j = 0; j < 4; ++j) { m_[j] = -1e30f; s_[j] = 0.f; }

  int rot = 0;

  for (int rt = 0; rt < 16; ++rt) {
    const int r0 = rt * 64;
    __syncthreads();  // barrier1: staged K/E visible; prev PV done reading Vl

    // issue V staging for CURRENT tile (drains at barrier2)
#pragma unroll
    for (int i = 0; i < 2; ++i) {
      int li = w * 2 + i;
      int dr = li * 8 + rsub;
      __builtin_amdgcn_global_load_lds(
          (gv_t*)(VTg + (size_t)(bh * 64 + dr) * 1024 + r0 + ((csub ^ (dr & 7)) << 3)),
          (lv_t*)(Vl + li * 512), 16, 0, 0);
    }

    // E A-operand frags for T2 (global dd-tiles 2w, 2w+1)
    short8 ea[2][2];
#pragma unroll
    for (int d2 = 0; d2 < 2; ++d2) {
      int row = (2 * w + d2) * 16 + m;
      int phys = (row + rot) & 127;
#pragma unroll
      for (int hh = 0; hh < 2; ++hh)
        ea[d2][hh] = *reinterpret_cast<const short8*>(
            El + phys * 64 + (((g + 4 * hh) ^ (row & 7)) << 3));
    }

    // QK^T + T2 (transposed-output) per f-tile
    f32x4 sc[4];
#pragma unroll
    for (int ft = 0; ft < 4; ++ft) {
      int kr = ft * 16 + m;
      short8 kb0 = *reinterpret_cast<const short8*>(Kl + kr * 64 + ((g ^ (kr & 7)) << 3));
      short8 kb1 = *reinterpret_cast<const short8*>(Kl + kr * 64 + (((g + 4) ^ (kr & 7)) << 3));
      f32x4 z = {0.f, 0.f, 0.f, 0.f};
      sc[ft] = __builtin_amdgcn_mfma_f32_16x16x32_bf16(qf1, kb1,
               __builtin_amdgcn_mfma_f32_16x16x32_bf16(qf0, kb0, z, 0, 0, 0), 0, 0, 0);
#pragma unroll
      for (int d2 = 0; d2 < 2; ++d2) {
        f32x4 t2 = __builtin_amdgcn_mfma_f32_16x16x32_bf16(ea[d2][1], kb1,
                   __builtin_amdgcn_mfma_f32_16x16x32_bf16(ea[d2][0], kb0, z, 0, 0, 0), 0, 0, 0);
        u32x2 pk;
        pk[0] = (unsigned)f2bf(t2[0]) | ((unsigned)f2bf(t2[1]) << 16);
        pk[1] = (unsigned)f2bf(t2[2]) | ((unsigned)f2bf(t2[3]) << 16);
        *reinterpret_cast<u32x2*>(T2s + (ft * 16 + m) * 132 + (2 * w + d2) * 16 + g4) = pk;
      }
    }

    // T1 local-window frags, in-register (wave w needs dd in [16w, 16w+79))
    f32x4 t1loc[5];
#pragma unroll
    for (int lti = 0; lti < 5; ++lti) {
      int row = (w + lti) * 16 + m;
      int phys = (row + rot) & 127;
      short8 e0 = *reinterpret_cast<const short8*>(El + phys * 64 + ((g ^ (row & 7)) << 3));
      short8 e1 = *reinterpret_cast<const short8*>(El + phys * 64 + (((g + 4) ^ (row & 7)) << 3));
      f32x4 z = {0.f, 0.f, 0.f, 0.f};
      t1loc[lti] = __builtin_amdgcn_mfma_f32_16x16x32_bf16(qf1, e1,
                   __builtin_amdgcn_mfma_f32_16x16x32_bf16(qf0, e0, z, 0, 0, 0), 0, 0, 0);
    }

    __syncthreads();  // barrier2: V staged + T2s visible; Kl/El readers done

    // issue K/E staging for NEXT tile (hides under gather/softmax/PV)
    if (rt < 15) {
      const int r0n = r0 + 64;
#pragma unroll
      for (int i = 0; i < 2; ++i) {
        int li = w * 2 + i;
        int kr = li * 8 + rsub;
        __builtin_amdgcn_global_load_lds(
            (gv_t*)(Kg + (size_t)(b * 1024 + r0n + kr) * 3072 + h * 64 + ((csub ^ (kr & 7)) << 3)),
            (lv_t*)(Kl + li * 512), 16, 0, 0);
        int rn = li * 8 + rsub;
        int p = l0 + 960 - 64 * (rt + 1) + rn;  // always in [0,1919]
        __builtin_amdgcn_global_load_lds(
            (gv_t*)(E + (size_t)p * 64 + ((csub ^ (rn & 7)) << 3)),
            (lv_t*)(El + ((rot + 64) & 127) * 64 + li * 512), 16, 0, 0);
      }
    }

    // S assembly: QK^T + gathered bias1 (shfl) + bias2 (imm-offset LDS), scale, mask
    float sv[4][4];
#pragma unroll
    for (int ct = 0; ct < 4; ++ct) {
      float mk = maskrow[r0 + ct * 16 + m];
#pragma unroll
      for (int j = 0; j < 4; ++j) {
        float t2v = bf2f(T2s[A0 + 2096 * ct + j]);
        float val = bsel[j] ? t1loc[4 - ct][j] : t1loc[3 - ct][j];
        float t1v = __shfl(val, srcl[j]);
        sv[ct][j] = (sc[ct][j] + t1v + t2v) * 0.125f + mk;
      }
    }

    // online softmax (row lives across the 16 lanes of a group)
#pragma unroll
    for (int j = 0; j < 4; ++j) {
      float rm = fmaxf(fmaxf(sv[0][j], sv[1][j]), fmaxf(sv[2][j], sv[3][j]));
      rm = fmaxf(rm, __shfl_xor(rm, 1));
      rm = fmaxf(rm, __shfl_xor(rm, 2));
      rm = fmaxf(rm, __shfl_xor(rm, 4));
      rm = fmaxf(rm, __shfl_xor(rm, 8));
      float mn = fmaxf(m_[j], rm);
      float al = __expf(m_[j] - mn);
      float rs = 0.f;
#pragma unroll
      for (int ct = 0; ct < 4; ++ct) {
        float p = __expf(sv[ct][j] - mn);
        sv[ct][j] = p; rs += p;
      }
      rs += __shfl_xor(rs, 1); rs += __shfl_xor(rs, 2);
      rs += __shfl_xor(rs, 4); rs += __shfl_xor(rs, 8);
      s_[j] = s_[j] * al + rs;
      m_[j] = mn;
#pragma unroll
      for (int vt = 0; vt < 4; ++vt) o_[vt][j] *= al;
    }

    // P -> wave-private LDS, row-major [e][f] with chunk XOR swizzle (round-1 mechanism)
#pragma unroll
    for (int ct = 0; ct < 4; ++ct)
#pragma unroll
      for (int j = 0; j < 4; ++j) {
        int e = g4 + j;
        int f = ct * 16 + m;
        Pp[w * 1024 + e * 64 + ((((f >> 3) ^ (e & 7)) << 3) | (f & 7))] = f2bf(sv[ct][j]);
      }

    // PV: A = P rows (b128), B = V^T rows (b128) — compiler-ordered LDS
    {
      short8 pf0 = *reinterpret_cast<const short8*>(Pp + w * 1024 + m * 64 + ((g ^ (m & 7)) << 3));
      short8 pf1 = *reinterpret_cast<const short8*>(Pp + w * 1024 + m * 64 + (((g + 4) ^ (m & 7)) << 3));
#pragma unroll
      for (int vt = 0; vt < 4; ++vt) {
        int dr = vt * 16 + m;
        short8 vb0 = *reinterpret_cast<const short8*>(Vl + dr * 64 + ((g ^ (dr & 7)) << 3));
        short8 vb1 = *reinterpret_cast<const short8*>(Vl + dr * 64 + (((g + 4) ^ (dr & 7)) << 3));
        o_[vt] = __builtin_amdgcn_mfma_f32_16x16x32_bf16(pf0, vb0, o_[vt], 0, 0, 0);
        o_[vt] = __builtin_amdgcn_mfma_f32_16x16x32_bf16(pf1, vb1, o_[vt], 0, 0, 0);
      }
    }

    rot = (rot + 64) & 127;
  }

  // epilogue: O / s
#pragma unroll
  for (int j = 0; j < 4; ++j) {
    float inv = 1.0f / s_[j];
    int row = b * 1024 + l0 + w * 16 + g4 + j;
#pragma unroll
    for (int vt = 0; vt < 4; ++vt)
      out[(size_t)row * 1024 + h * 64 + vt * 16 + m] = o_[vt][j] * inv;
  }
}

// ---------------- host launch ----------------
extern "C" void kernel_launch(void* const* d_in, const int* in_sizes, int n_in,
                              void* d_out, int out_size, void* d_ws, size_t ws_size,
                              hipStream_t stream) {
  const float* hidden = (const float*)d_in[0];
  const float* mask   = (const float*)d_in[1];
  const float* Wq = (const float*)d_in[2];
  const float* bq = (const float*)d_in[3];
  const float* Wk = (const float*)d_in[4];
  const float* bk = (const float*)d_in[5];
  const float* Wv = (const float*)d_in[6];
  const float* bv = (const float*)d_in[7];
  const float* dist = (const float*)d_in[8];
  float* out = (float*)d_out;

  char* ws = (char*)d_ws;
  ushort* Hbf  = (ushort*)(ws);                                      //  8,388,608 (reused as VT after GEMM)
  ushort* Wqkv = (ushort*)(ws + 8388608);                            //  6,291,456
  float*  Bqkv = (float*) (ws + 8388608 + 6291456);                  //     16,384
  ushort* Ebf  = (ushort*)(ws + 8388608 + 6291456 + 16384);          //    262,144
  ushort* QKV  = (ushort*)(ws + 8388608 + 6291456 + 16384 + 262144); // 25,165,824
  ushort* VT   = Hbf;  // V^T [(b*16+h)*64 + d][l], exactly 8,388,608 B

  k_cvt4<<<4096, 256, 0, stream>>>(hidden, Hbf, 1048576);
  k_cvt4<<<1024, 256, 0, stream>>>(Wq, Wqkv,           262144);
  k_cvt4<<<1024, 256, 0, stream>>>(Wk, Wqkv + 1048576, 262144);
  k_cvt4<<<1024, 256, 0, stream>>>(Wv, Wqkv + 2097152, 262144);
  k_cvt4<<<128,  256, 0, stream>>>(dist, Ebf, 32752);
  k_bias<<<12,   256, 0, stream>>>(bq, bk, bv, Bqkv);

  k_gemm_qkv<<<dim3(24, 32), 256, 0, stream>>>(Hbf, Wqkv, Bqkv, QKV);
  k_vt<<<dim3(16, 64), 256, 0, stream>>>(QKV, VT);
  k_attn<<<dim3(16, 16, 4), 256, 0, stream>>>(QKV, VT, Ebf, mask, out);
}

// Round 4
// 178.246 us; speedup vs baseline: 1.3117x; 1.1268x over previous
//
#include <hip/hip_runtime.h>

typedef __attribute__((ext_vector_type(4))) float f32x4;
typedef __attribute__((ext_vector_type(8))) short short8;
typedef __attribute__((ext_vector_type(2))) unsigned u32x2;

typedef __attribute__((address_space(1))) const void gv_t;
typedef __attribute__((address_space(3))) void lv_t;

__device__ __forceinline__ ushort f2bf(float f) {
  union { float f; unsigned u; } v; v.f = f;
  unsigned r = v.u + 0x7fffu + ((v.u >> 16) & 1u);
  return (ushort)(r >> 16);
}
__device__ __forceinline__ float bf2f(ushort u) {
  union { unsigned u; float f; } v; v.u = ((unsigned)u) << 16;
  return v.f;
}

// ---------------- fused prep: all bf16 conversions + bias copy, one launch ----
__global__ void k_prep(const float* __restrict__ hidden, const float* __restrict__ Wq,
                       const float* __restrict__ Wk, const float* __restrict__ Wv,
                       const float* __restrict__ dist, const float* __restrict__ bq,
                       const float* __restrict__ bk, const float* __restrict__ bv,
                       ushort* __restrict__ Hbf, ushort* __restrict__ Wqkv,
                       ushort* __restrict__ Ebf, float* __restrict__ Bqkv) {
  int i = blockIdx.x * blockDim.x + threadIdx.x;
  const float* src; ushort* dst; int o;
  if (i < 1048576)      { src = hidden; o = i;            dst = Hbf; }
  else if (i < 1310720) { src = Wq;   o = i - 1048576;    dst = Wqkv; }
  else if (i < 1572864) { src = Wk;   o = i - 1310720;    dst = Wqkv + 1048576; }
  else if (i < 1835008) { src = Wv;   o = i - 1572864;    dst = Wqkv + 2097152; }
  else if (i < 1867760) { src = dist; o = i - 1835008;    dst = Ebf; }
  else if (i < 1868528) {
    int ib = i - 1867760;
    const float* bs = ib < 256 ? bq : (ib < 512 ? bk : bv);
    reinterpret_cast<float4*>(Bqkv)[ib] = reinterpret_cast<const float4*>(bs)[ib & 255];
    return;
  } else return;
  float4 v = reinterpret_cast<const float4*>(src)[o];
  ushort4 u;
  u.x = f2bf(v.x); u.y = f2bf(v.y); u.z = f2bf(v.z); u.w = f2bf(v.w);
  reinterpret_cast<ushort4*>(dst)[o] = u;
}

// ---------------- fused QKV projection GEMM (m97 structure, unchanged) --------
__global__ __launch_bounds__(256) void k_gemm_qkv(
    const ushort* __restrict__ A, const ushort* __restrict__ W,
    const float* __restrict__ bias, ushort* __restrict__ C)
{
  __shared__ __align__(16) ushort As[128 * 32];
  __shared__ __align__(16) ushort Bs[128 * 32];
  const int n0 = blockIdx.x * 128;
  const int m0 = blockIdx.y * 128;
  const int tid = threadIdx.x;
  const int w = tid >> 6, lane = tid & 63;
  const int wr = (w >> 1) * 64, wc = (w & 1) * 64;
  const int lr = lane & 15, lk = (lane >> 4) * 8;

  f32x4 acc[4][4] = {};

  for (int k0 = 0; k0 < 1024; k0 += 32) {
    __syncthreads();
#pragma unroll
    for (int inst = 0; inst < 2; ++inst) {
      int chunk = w * 128 + inst * 64 + lane;
      int row = chunk >> 2, c8 = (chunk & 3) * 8;
      __builtin_amdgcn_global_load_lds(
          (gv_t*)(A + (size_t)(m0 + row) * 1024 + k0 + c8),
          (lv_t*)(As + (size_t)(w * 128 + inst * 64) * 8), 16, 0, 0);
      __builtin_amdgcn_global_load_lds(
          (gv_t*)(W + (size_t)(n0 + row) * 1024 + k0 + c8),
          (lv_t*)(Bs + (size_t)(w * 128 + inst * 64) * 8), 16, 0, 0);
    }
    __syncthreads();
    short8 af[4], bfr[4];
#pragma unroll
    for (int t = 0; t < 4; ++t) {
      af[t]  = *reinterpret_cast<const short8*>(As + (wr + t * 16 + lr) * 32 + lk);
      bfr[t] = *reinterpret_cast<const short8*>(Bs + (wc + t * 16 + lr) * 32 + lk);
    }
#pragma unroll
    for (int mt = 0; mt < 4; ++mt)
#pragma unroll
      for (int nt = 0; nt < 4; ++nt)
        acc[mt][nt] = __builtin_amdgcn_mfma_f32_16x16x32_bf16(af[mt], bfr[nt], acc[mt][nt], 0, 0, 0);
  }

  float bv[4];
#pragma unroll
  for (int nt = 0; nt < 4; ++nt) bv[nt] = bias[n0 + wc + nt * 16 + lr];
#pragma unroll
  for (int mt = 0; mt < 4; ++mt)
#pragma unroll
    for (int nt = 0; nt < 4; ++nt)
#pragma unroll
      for (int j = 0; j < 4; ++j) {
        int row = m0 + wr + mt * 16 + (lane >> 4) * 4 + j;
        int col = n0 + wc + nt * 16 + lr;
        C[(size_t)row * 3072 + col] = f2bf(acc[mt][nt][j] + bv[nt]);
      }
}

// ---------------- V transpose: QKV V-slice -> VT[(b*16+h)*64 + d][l] ----------
__global__ __launch_bounds__(256) void k_vt(const ushort* __restrict__ QKV,
                                            ushort* __restrict__ VT) {
  __shared__ ushort t[64][65];
  const int bh = blockIdx.y, b = bh >> 4, h = bh & 15;
  const int l0 = blockIdx.x * 64;
  const int r = threadIdx.x >> 2, c0 = (threadIdx.x & 3) * 16;
  const ushort* src = QKV + (size_t)(b * 1024 + l0 + r) * 3072 + 2048 + h * 64 + c0;
  short8 v0 = *reinterpret_cast<const short8*>(src);
  short8 v1 = *reinterpret_cast<const short8*>(src + 8);
#pragma unroll
  for (int i = 0; i < 8; ++i) {
    t[c0 + i][r] = (ushort)v0[i];
    t[c0 + 8 + i][r] = (ushort)v1[i];
  }
  __syncthreads();
  short8 o0, o1;
#pragma unroll
  for (int i = 0; i < 8; ++i) {
    o0[i] = (short)t[r][c0 + i];
    o1[i] = (short)t[r][c0 + 8 + i];
  }
  ushort* dst = VT + (size_t)(bh * 64 + r) * 1024 + l0 + c0;
  *reinterpret_cast<short8*>(dst) = o0;
  *reinterpret_cast<short8*>(dst + 8) = o1;
}

// ---------------- fused attention, 2 l-tiles/block, 8 waves -------------------
// grid (L/128, H, B), 512 threads. Wave w owns q-rows [l0+16w, l0+16w+16).
// Shared K/V/E/T2 across all 8 waves; per-wave math identical to round 3.
// E window = 191 diagonals in a 256-row circular buffer; T2s[f][dd] stride 196;
// P aliases first 8KB of T2s (extra barrier before stores).
__global__ __launch_bounds__(512, 4) void k_attn(
    const ushort* __restrict__ QKV, const ushort* __restrict__ VTg,
    const ushort* __restrict__ E, const float* __restrict__ mask,
    float* __restrict__ out)
{
  __shared__ __align__(16) ushort Kl[64 * 64];     //  8 KB
  __shared__ __align__(16) ushort Vl[64 * 64];     //  8 KB
  __shared__ __align__(16) ushort El[256 * 64];    // 32 KB circular E window
  __shared__ __align__(16) ushort T2s[64 * 196];   // 24.5 KB; first 8192 elems alias P

  const int lt = blockIdx.x, h = blockIdx.y, b = blockIdx.z;
  const int bh = b * 16 + h;
  const int l0 = lt * 128;
  const int tid = threadIdx.x;
  const int w = tid >> 6, lane = tid & 63;
  const int g = lane >> 4, m = lane & 15, g4 = g * 4;
  const int rsub = lane >> 3, csub = lane & 7;

  const ushort* Qg = QKV;
  const ushort* Kg = QKV + 1024;
  const float* maskrow = mask + b * 1024;

  // Q fragments (reused all r-tiles)
  short8 qf0, qf1;
  {
    const size_t qoff = (size_t)(b * 1024 + l0 + w * 16 + m) * 3072 + h * 64;
    qf0 = *reinterpret_cast<const short8*>(Qg + qoff + g * 8);
    qf1 = *reinterpret_cast<const short8*>(Qg + qoff + 32 + g * 8);
  }

  // hoisted T1-gather constants (round-3 verified)
  int srcl[4], bsel[4];
#pragma unroll
  for (int j = 0; j < 4; ++j) {
    int x = (g4 + j + 63 - m) & 15;
    srcl[j] = (lane & 48) | x;
    bsel[j] = (g4 + j) > x;
  }
  // T2 gather: elem addr = A0 + 3120*ct + j   (addr = (16ct+m)*196 + dd)
  const int A0 = 195 * m + 16 * w + g4 + 63;
  // T2 dd-tile assignment: waves 0-3 -> {2w,2w+1}; waves 4-7 -> {w+4}
  const int tile0 = (w < 4) ? 2 * w : 4 + w;

  // ---- prologue staging: K tile 0 (8 instr), E window rows 0..191 (24 instr)
  {
    int kr = w * 8 + rsub;
    __builtin_amdgcn_global_load_lds(
        (gv_t*)(Kg + (size_t)(b * 1024 + kr) * 3072 + h * 64 + ((csub ^ (kr & 7)) << 3)),
        (lv_t*)(Kl + w * 512), 16, 0, 0);
#pragma unroll
    for (int i = 0; i < 3; ++i) {
      int li = w * 3 + i;
      int er = li * 8 + rsub;
      int p = l0 + 960 + er; if (p > 2046) p = 2046;  // clamped row never gathered
      __builtin_amdgcn_global_load_lds(
          (gv_t*)(E + (size_t)p * 64 + ((csub ^ (er & 7)) << 3)),
          (lv_t*)(El + li * 512), 16, 0, 0);
    }
  }

  f32x4 o_[4] = {};
  float m_[4], s_[4];
#pragma unroll
  for (int j = 0; j < 4; ++j) { m_[j] = -1e30f; s_[j] = 0.f; }

  int rot = 0;

  for (int rt = 0; rt < 16; ++rt) {
    const int r0 = rt * 64;
    __syncthreads();  // B1: K/E(cur) staged visible; Vl free (prev PV done)

    // V stage (cur) — drains at B2
    {
      int dr = w * 8 + rsub;
      __builtin_amdgcn_global_load_lds(
          (gv_t*)(VTg + (size_t)(bh * 64 + dr) * 1024 + r0 + ((csub ^ (dr & 7)) << 3)),
          (lv_t*)(Vl + w * 512), 16, 0, 0);
    }

    // E A-operand frags for this wave's T2 dd-tiles
    short8 ea0[2], ea1[2];
    {
      int row = tile0 * 16 + m, phys = (row + rot) & 255;
      ea0[0] = *reinterpret_cast<const short8*>(El + phys * 64 + ((g ^ (row & 7)) << 3));
      ea0[1] = *reinterpret_cast<const short8*>(El + phys * 64 + (((g + 4) ^ (row & 7)) << 3));
    }
    if (w < 4) {
      int row = (tile0 + 1) * 16 + m, phys = (row + rot) & 255;
      ea1[0] = *reinterpret_cast<const short8*>(El + phys * 64 + ((g ^ (row & 7)) << 3));
      ea1[1] = *reinterpret_cast<const short8*>(El + phys * 64 + (((g + 4) ^ (row & 7)) << 3));
    }

    // QK^T + T2 (transposed-output) per f-tile
    f32x4 sc[4];
#pragma unroll
    for (int ft = 0; ft < 4; ++ft) {
      int kr = ft * 16 + m;
      short8 kb0 = *reinterpret_cast<const short8*>(Kl + kr * 64 + ((g ^ (kr & 7)) << 3));
      short8 kb1 = *reinterpret_cast<const short8*>(Kl + kr * 64 + (((g + 4) ^ (kr & 7)) << 3));
      f32x4 z = {0.f, 0.f, 0.f, 0.f};
      sc[ft] = __builtin_amdgcn_mfma_f32_16x16x32_bf16(qf1, kb1,
               __builtin_amdgcn_mfma_f32_16x16x32_bf16(qf0, kb0, z, 0, 0, 0), 0, 0, 0);
      {
        f32x4 t2 = __builtin_amdgcn_mfma_f32_16x16x32_bf16(ea0[1], kb1,
                   __builtin_amdgcn_mfma_f32_16x16x32_bf16(ea0[0], kb0, z, 0, 0, 0), 0, 0, 0);
        u32x2 pk;
        pk[0] = (unsigned)f2bf(t2[0]) | ((unsigned)f2bf(t2[1]) << 16);
        pk[1] = (unsigned)f2bf(t2[2]) | ((unsigned)f2bf(t2[3]) << 16);
        *reinterpret_cast<u32x2*>(T2s + (ft * 16 + m) * 196 + tile0 * 16 + g4) = pk;
      }
      if (w < 4) {
        f32x4 t2 = __builtin_amdgcn_mfma_f32_16x16x32_bf16(ea1[1], kb1,
                   __builtin_amdgcn_mfma_f32_16x16x32_bf16(ea1[0], kb0, z, 0, 0, 0), 0, 0, 0);
        u32x2 pk;
        pk[0] = (unsigned)f2bf(t2[0]) | ((unsigned)f2bf(t2[1]) << 16);
        pk[1] = (unsigned)f2bf(t2[2]) | ((unsigned)f2bf(t2[3]) << 16);
        *reinterpret_cast<u32x2*>(T2s + (ft * 16 + m) * 196 + (tile0 + 1) * 16 + g4) = pk;
      }
    }

    // T1 local-window frags, in-register (wave w needs dd in [16w, 16w+79))
    f32x4 t1loc[5];
#pragma unroll
    for (int lti = 0; lti < 5; ++lti) {
      int row = (w + lti) * 16 + m, phys = (row + rot) & 255;
      short8 e0 = *reinterpret_cast<const short8*>(El + phys * 64 + ((g ^ (row & 7)) << 3));
      short8 e1 = *reinterpret_cast<const short8*>(El + phys * 64 + (((g + 4) ^ (row & 7)) << 3));
      f32x4 z = {0.f, 0.f, 0.f, 0.f};
      t1loc[lti] = __builtin_amdgcn_mfma_f32_16x16x32_bf16(qf1, e1,
                   __builtin_amdgcn_mfma_f32_16x16x32_bf16(qf0, e0, z, 0, 0, 0), 0, 0, 0);
    }

    __syncthreads();  // B2: T2s + Vl visible; Kl/El phase-1 readers done

    // stage next K tile + next 64 E rows (dest rows disjoint from live window)
    if (rt < 15) {
      int kr = w * 8 + rsub;
      __builtin_amdgcn_global_load_lds(
          (gv_t*)(Kg + (size_t)(b * 1024 + r0 + 64 + kr) * 3072 + h * 64 + ((csub ^ (kr & 7)) << 3)),
          (lv_t*)(Kl + w * 512), 16, 0, 0);
      int X = (rot + 192) & 255;
      int er = w * 8 + rsub;
      int p = l0 + 960 - 64 * (rt + 1) + er;  // in [0,1855], no clamp needed
      __builtin_amdgcn_global_load_lds(
          (gv_t*)(E + (size_t)p * 64 + ((csub ^ (er & 7)) << 3)),
          (lv_t*)(El + (X + w * 8) * 64), 16, 0, 0);
    }

    // S assembly: QK^T + bias1 (shfl from t1loc) + bias2 (imm-offset T2s), scale, mask
    float sv[4][4];
#pragma unroll
    for (int ct = 0; ct < 4; ++ct) {
      float mk = maskrow[r0 + ct * 16 + m];
#pragma unroll
      for (int j = 0; j < 4; ++j) {
        float t2v = bf2f(T2s[A0 + 3120 * ct + j]);
        float val = bsel[j] ? t1loc[4 - ct][j] : t1loc[3 - ct][j];
        float t1v = __shfl(val, srcl[j]);
        sv[ct][j] = (sc[ct][j] + t1v + t2v) * 0.125f + mk;
      }
    }

    // online softmax (row lives across the 16 lanes of a group)
#pragma unroll
    for (int j = 0; j < 4; ++j) {
      float rm = fmaxf(fmaxf(sv[0][j], sv[1][j]), fmaxf(sv[2][j], sv[3][j]));
      rm = fmaxf(rm, __shfl_xor(rm, 1));
      rm = fmaxf(rm, __shfl_xor(rm, 2));
      rm = fmaxf(rm, __shfl_xor(rm, 4));
      rm = fmaxf(rm, __shfl_xor(rm, 8));
      float mn = fmaxf(m_[j], rm);
      float al = __expf(m_[j] - mn);
      float rs = 0.f;
#pragma unroll
      for (int ct = 0; ct < 4; ++ct) {
        float p = __expf(sv[ct][j] - mn);
        sv[ct][j] = p; rs += p;
      }
      rs += __shfl_xor(rs, 1); rs += __shfl_xor(rs, 2);
      rs += __shfl_xor(rs, 4); rs += __shfl_xor(rs, 8);
      s_[j] = s_[j] * al + rs;
      m_[j] = mn;
#pragma unroll
      for (int vt = 0; vt < 4; ++vt) o_[vt][j] *= al;
    }

    __syncthreads();  // B2.5: all waves' T2s gather reads complete — alias safe

    // P -> LDS (alias over T2s), row-major [e][f] with chunk XOR swizzle
    ushort* Pp = (ushort*)T2s;
#pragma unroll
    for (int ct = 0; ct < 4; ++ct)
#pragma unroll
      for (int j = 0; j < 4; ++j) {
        int e = g4 + j;
        int f = ct * 16 + m;
        Pp[w * 1024 + e * 64 + ((((f >> 3) ^ (e & 7)) << 3) | (f & 7))] = f2bf(sv[ct][j]);
      }

    // PV: A = P rows (b128), B = V^T rows (b128)
    {
      short8 pf0 = *reinterpret_cast<const short8*>(Pp + w * 1024 + m * 64 + ((g ^ (m & 7)) << 3));
      short8 pf1 = *reinterpret_cast<const short8*>(Pp + w * 1024 + m * 64 + (((g + 4) ^ (m & 7)) << 3));
#pragma unroll
      for (int vt = 0; vt < 4; ++vt) {
        int dr = vt * 16 + m;
        short8 vb0 = *reinterpret_cast<const short8*>(Vl + dr * 64 + ((g ^ (dr & 7)) << 3));
        short8 vb1 = *reinterpret_cast<const short8*>(Vl + dr * 64 + (((g + 4) ^ (dr & 7)) << 3));
        o_[vt] = __builtin_amdgcn_mfma_f32_16x16x32_bf16(pf0, vb0, o_[vt], 0, 0, 0);
        o_[vt] = __builtin_amdgcn_mfma_f32_16x16x32_bf16(pf1, vb1, o_[vt], 0, 0, 0);
      }
    }

    rot = (rot + 192) & 255;
  }

  // epilogue: O / s
#pragma unroll
  for (int j = 0; j < 4; ++j) {
    float inv = 1.0f / s_[j];
    int row = b * 1024 + l0 + w * 16 + g4 + j;
#pragma unroll
    for (int vt = 0; vt < 4; ++vt)
      out[(size_t)row * 1024 + h * 64 + vt * 16 + m] = o_[vt][j] * inv;
  }
}

// ---------------- host launch ----------------
extern "C" void kernel_launch(void* const* d_in, const int* in_sizes, int n_in,
                              void* d_out, int out_size, void* d_ws, size_t ws_size,
                              hipStream_t stream) {
  const float* hidden = (const float*)d_in[0];
  const float* mask   = (const float*)d_in[1];
  const float* Wq = (const float*)d_in[2];
  const float* bq = (const float*)d_in[3];
  const float* Wk = (const float*)d_in[4];
  const float* bk = (const float*)d_in[5];
  const float* Wv = (const float*)d_in[6];
  const float* bv = (const float*)d_in[7];
  const float* dist = (const float*)d_in[8];
  float* out = (float*)d_out;

  char* ws = (char*)d_ws;
  ushort* Hbf  = (ushort*)(ws);                                      //  8,388,608 (reused as VT)
  ushort* Wqkv = (ushort*)(ws + 8388608);                            //  6,291,456
  float*  Bqkv = (float*) (ws + 8388608 + 6291456);                  //     16,384
  ushort* Ebf  = (ushort*)(ws + 8388608 + 6291456 + 16384);          //    262,144
  ushort* QKV  = (ushort*)(ws + 8388608 + 6291456 + 16384 + 262144); // 25,165,824
  ushort* VT   = Hbf;  // V^T [(b*16+h)*64 + d][l]

  k_prep<<<7299, 256, 0, stream>>>(hidden, Wq, Wk, Wv, dist, bq, bk, bv,
                                   Hbf, Wqkv, Ebf, Bqkv);
  k_gemm_qkv<<<dim3(24, 32), 256, 0, stream>>>(Hbf, Wqkv, Bqkv, QKV);
  k_vt<<<dim3(16, 64), 256, 0, stream>>>(QKV, VT);
  k_attn<<<dim3(8, 16, 4), 512, 0, stream>>>(QKV, VT, Ebf, mask, out);
}